// Round 1
// baseline (356.384 us; speedup 1.0000x reference)
//
#include <hip/hip_runtime.h>
#include <math.h>

#define POS_W 1.0f
#define ANG_W 1.0f
#define WID_W 1.0f

__device__ __forceinline__ float smooth_l1(float x) {
    float a = fabsf(x);
    return a < 1.0f ? 0.5f * x * x : a - 0.5f;
}

// ---------------------------------------------------------------------------
// Kernel A: per-block (256 counts) sums
// ---------------------------------------------------------------------------
__global__ void k_block_sums(const int* __restrict__ counts, int stride, int n,
                             int* __restrict__ blockSums) {
    int i = blockIdx.x * 256 + threadIdx.x;
    int c = (i < n) ? counts[(long long)i * stride] : 0;
    // wave64 reduce
    for (int off = 32; off > 0; off >>= 1) c += __shfl_down(c, off, 64);
    __shared__ int sdata[4];
    int lane = threadIdx.x & 63, wave = threadIdx.x >> 6;
    if (lane == 0) sdata[wave] = c;
    __syncthreads();
    if (threadIdx.x == 0)
        blockSums[blockIdx.x] = sdata[0] + sdata[1] + sdata[2] + sdata[3];
}

// ---------------------------------------------------------------------------
// Kernel B: single-block exclusive scan of blockSums[nb] -> blockOffs[nb]
// ---------------------------------------------------------------------------
__global__ void k_scan_blocks(const int* __restrict__ blockSums, int nb,
                              int* __restrict__ blockOffs) {
    int t = threadIdx.x;
    int per = (nb + 255) / 256;
    int start = t * per;
    int end = min(start + per, nb);
    int sum = 0;
    for (int j = start; j < end; ++j) sum += blockSums[j];
    __shared__ int s[256];
    s[t] = sum;
    __syncthreads();
    // Hillis-Steele inclusive scan over 256 per-thread totals
    for (int d = 1; d < 256; d <<= 1) {
        int v = (t >= d) ? s[t - d] : 0;
        __syncthreads();
        s[t] += v;
        __syncthreads();
    }
    int run = s[t] - sum;  // exclusive prefix for this thread's chunk
    for (int j = start; j < end; ++j) {
        blockOffs[j] = run;
        run += blockSums[j];
    }
}

// ---------------------------------------------------------------------------
// Kernel C: main loss kernel. One thread per prediction.
// ---------------------------------------------------------------------------
__global__ void k_loss(const float* __restrict__ pred,
                       const float* __restrict__ tgt,
                       const int* __restrict__ counts, int stride, int n,
                       const int* __restrict__ blockOffs, float invN,
                       float* __restrict__ out) {
    int t = threadIdx.x;
    int i = blockIdx.x * 256 + t;
    int c = (i < n) ? counts[(long long)i * stride] : 0;

    // block-level exclusive scan of counts -> per-thread offset within block
    __shared__ int s[256];
    s[t] = c;
    __syncthreads();
    for (int d = 1; d < 256; d <<= 1) {
        int v = (t >= d) ? s[t - d] : 0;
        __syncthreads();
        s[t] += v;
        __syncthreads();
    }
    int off = blockOffs[blockIdx.x] + s[t] - c;

    float loss = 0.0f;
    if (i < n && c > 0) {
        const float* p = pred + (long long)i * 6;
        float p0 = p[0], p1 = p[1], p2 = p[2], p3 = p[3], p4 = p[4];
        float best = INFINITY;
        float b0 = 0, b1 = 0, b2 = 0, b3 = 0, b4 = 0;
        const float* g = tgt + (long long)off * 6;
        for (int k = 0; k < c; ++k) {
            float g0 = g[0], g1 = g[1], g2 = g[2], g3 = g[3], g4 = g[4];
            float d0 = p0 - g0, d1 = p1 - g1, d2 = p2 - g2, d3 = p3 - g3,
                  d4 = p4 - g4;
            float dist = POS_W * (d0 * d0 + d1 * d1) +
                         ANG_W * (d2 * d2 + d3 * d3) + WID_W * d4 * d4;
            if (dist < best) {  // strict < keeps FIRST occurrence (matches ref)
                best = dist;
                b0 = g0; b1 = g1; b2 = g2; b3 = g3; b4 = g4;
            }
            g += 6;
        }
        loss = POS_W * (smooth_l1(p0 - b0) + smooth_l1(p1 - b1)) +
               ANG_W * (fabsf(p2 - b2) + fabsf(p3 - b3)) +
               WID_W * smooth_l1(p4 - b4);
    }

    // block reduce (wave64 shuffle + LDS across 4 waves)
    for (int o = 32; o > 0; o >>= 1) loss += __shfl_down(loss, o, 64);
    __shared__ float fs[4];
    int lane = t & 63, wave = t >> 6;
    if (lane == 0) fs[wave] = loss;
    __syncthreads();
    if (t == 0) {
        float tot = (fs[0] + fs[1] + fs[2] + fs[3]) * invN;
        atomicAdd(out, tot);
    }
}

// ---------------------------------------------------------------------------
extern "C" void kernel_launch(void* const* d_in, const int* in_sizes, int n_in,
                              void* d_out, int out_size, void* d_ws,
                              size_t ws_size, hipStream_t stream) {
    const float* pred = (const float*)d_in[0];
    const float* tgt = (const float*)d_in[1];
    const int* counts = (const int*)d_in[2];
    int n = in_sizes[0] / 6;
    // robustness: if counts arrived as int64, read the low word of each pair
    int stride = (in_sizes[2] == n) ? 1 : 2;
    int nb = (n + 255) / 256;

    int* blockSums = (int*)d_ws;
    int* blockOffs = blockSums + nb;
    float* out = (float*)d_out;

    hipMemsetAsync(d_out, 0, sizeof(float), stream);
    k_block_sums<<<nb, 256, 0, stream>>>(counts, stride, n, blockSums);
    k_scan_blocks<<<1, 256, 0, stream>>>(blockSums, nb, blockOffs);
    k_loss<<<nb, 256, 0, stream>>>(pred, tgt, counts, stride, n, blockOffs,
                                   1.0f / n, out);
}

// Round 2
// 339.155 us; speedup vs baseline: 1.0508x; 1.0508x over previous
//
#include <hip/hip_runtime.h>
#include <math.h>

#define POS_W 1.0f
#define ANG_W 1.0f
#define WID_W 1.0f
#define CHUNK 1024  // target rows per LDS chunk (24 KB)

__device__ __forceinline__ float smooth_l1(float x) {
    float a = fabsf(x);
    return a < 1.0f ? 0.5f * x * x : a - 0.5f;
}

// ---------------------------------------------------------------------------
// Kernel A: per-block (256 counts) sums
// ---------------------------------------------------------------------------
__global__ void k_block_sums(const int* __restrict__ counts, int stride, int n,
                             int* __restrict__ blockSums) {
    int i = blockIdx.x * 256 + threadIdx.x;
    int c = (i < n) ? counts[(long long)i * stride] : 0;
    for (int off = 32; off > 0; off >>= 1) c += __shfl_down(c, off, 64);
    __shared__ int sdata[4];
    int lane = threadIdx.x & 63, wave = threadIdx.x >> 6;
    if (lane == 0) sdata[wave] = c;
    __syncthreads();
    if (threadIdx.x == 0)
        blockSums[blockIdx.x] = sdata[0] + sdata[1] + sdata[2] + sdata[3];
}

// ---------------------------------------------------------------------------
// Kernel B: single-block exclusive scan of blockSums[nb] -> blockOffs[nb]
// ---------------------------------------------------------------------------
__global__ void k_scan_blocks(const int* __restrict__ blockSums, int nb,
                              int* __restrict__ blockOffs) {
    int t = threadIdx.x;
    int per = (nb + 255) / 256;
    int start = t * per;
    int end = min(start + per, nb);
    int sum = 0;
    for (int j = start; j < end; ++j) sum += blockSums[j];
    __shared__ int s[256];
    s[t] = sum;
    __syncthreads();
    for (int d = 1; d < 256; d <<= 1) {
        int v = (t >= d) ? s[t - d] : 0;
        __syncthreads();
        s[t] += v;
        __syncthreads();
    }
    int run = s[t] - sum;
    for (int j = start; j < end; ++j) {
        blockOffs[j] = run;
        run += blockSums[j];
    }
}

// ---------------------------------------------------------------------------
// Kernel C: main loss kernel. One thread per prediction; block's contiguous
// target window staged through LDS in CHUNK-row pieces with coalesced float2
// loads, ragged per-thread argmin scan served from LDS.
// ---------------------------------------------------------------------------
__global__ __launch_bounds__(256) void k_loss(
    const float* __restrict__ pred, const float* __restrict__ tgt,
    const int* __restrict__ counts, int stride, int n,
    const int* __restrict__ blockOffs, float invN, float* __restrict__ out) {
    __shared__ int s[256];
    __shared__ float2 ch[CHUNK * 3];  // 24 KB

    int t = threadIdx.x;
    int i = blockIdx.x * 256 + t;
    int c = (i < n) ? counts[(long long)i * stride] : 0;

    // block-level inclusive scan of counts
    s[t] = c;
    __syncthreads();
    for (int d = 1; d < 256; d <<= 1) {
        int v = (t >= d) ? s[t - d] : 0;
        __syncthreads();
        s[t] += v;
        __syncthreads();
    }
    int off = s[t] - c;    // exclusive prefix within block
    int total = s[255];    // rows this block consumes
    int winStart = blockOffs[blockIdx.x];

    bool active = (i < n) && (c > 0);
    float p0 = 0, p1 = 0, p2 = 0, p3 = 0, p4 = 0;
    if (active) {
        const float2* p2p = (const float2*)(pred + (long long)i * 6);
        float2 a = p2p[0], b = p2p[1], w = p2p[2];
        p0 = a.x; p1 = a.y; p2 = b.x; p3 = b.y; p4 = w.x;
    }

    float best = INFINITY;
    float b0 = 0, b1 = 0, b2 = 0, b3 = 0, b4 = 0;

    const float2* tgt2 = (const float2*)tgt;
    for (int base = 0; base < total; base += CHUNK) {
        int rows = min(CHUNK, total - base);
        const float2* src = tgt2 + (long long)(winStart + base) * 3;
        for (int k = t; k < rows * 3; k += 256) ch[k] = src[k];
        __syncthreads();
        if (active) {
            int lo = max(off, base), hi = min(off + c, base + rows);
            for (int r = lo; r < hi; ++r) {
                int l3 = (r - base) * 3;
                float2 ga = ch[l3], gb = ch[l3 + 1], gw = ch[l3 + 2];
                float d0 = p0 - ga.x, d1 = p1 - ga.y;
                float d2 = p2 - gb.x, d3 = p3 - gb.y;
                float d4 = p4 - gw.x;
                float dist = POS_W * (d0 * d0 + d1 * d1) +
                             ANG_W * (d2 * d2 + d3 * d3) + WID_W * d4 * d4;
                if (dist < best) {  // strict <: first occurrence, matches ref
                    best = dist;
                    b0 = ga.x; b1 = ga.y; b2 = gb.x; b3 = gb.y; b4 = gw.x;
                }
            }
        }
        __syncthreads();
    }

    float loss = 0.0f;
    if (active) {
        loss = POS_W * (smooth_l1(p0 - b0) + smooth_l1(p1 - b1)) +
               ANG_W * (fabsf(p2 - b2) + fabsf(p3 - b3)) +
               WID_W * smooth_l1(p4 - b4);
    }

    for (int o = 32; o > 0; o >>= 1) loss += __shfl_down(loss, o, 64);
    __shared__ float fs[4];
    int lane = t & 63, wave = t >> 6;
    if (lane == 0) fs[wave] = loss;
    __syncthreads();
    if (t == 0) {
        float tot = (fs[0] + fs[1] + fs[2] + fs[3]) * invN;
        atomicAdd(out, tot);
    }
}

// ---------------------------------------------------------------------------
extern "C" void kernel_launch(void* const* d_in, const int* in_sizes, int n_in,
                              void* d_out, int out_size, void* d_ws,
                              size_t ws_size, hipStream_t stream) {
    const float* pred = (const float*)d_in[0];
    const float* tgt = (const float*)d_in[1];
    const int* counts = (const int*)d_in[2];
    int n = in_sizes[0] / 6;
    int stride = (in_sizes[2] == n) ? 1 : 2;  // int64 counts -> read low words
    int nb = (n + 255) / 256;

    int* blockSums = (int*)d_ws;
    int* blockOffs = blockSums + nb;
    float* out = (float*)d_out;

    hipMemsetAsync(d_out, 0, sizeof(float), stream);
    k_block_sums<<<nb, 256, 0, stream>>>(counts, stride, n, blockSums);
    k_scan_blocks<<<1, 256, 0, stream>>>(blockSums, nb, blockOffs);
    k_loss<<<nb, 256, 0, stream>>>(pred, tgt, counts, stride, n, blockOffs,
                                   1.0f / n, out);
}

// Round 3
// 309.153 us; speedup vs baseline: 1.1528x; 1.0970x over previous
//
#include <hip/hip_runtime.h>
#include <math.h>

#define POS_W 1.0f
#define ANG_W 1.0f
#define WID_W 1.0f
#define CHUNK 1024         // target rows per LDS chunk (24 KB)
#define F2PT 12            // (CHUNK*3)/256 float2 per thread per chunk

__device__ __forceinline__ float smooth_l1(float x) {
    float a = fabsf(x);
    return a < 1.0f ? 0.5f * x * x : a - 0.5f;
}

// ---------------------------------------------------------------------------
// Kernel A: per-block (256 counts) sums
// ---------------------------------------------------------------------------
__global__ void k_block_sums(const int* __restrict__ counts, int stride, int n,
                             int* __restrict__ blockSums) {
    int i = blockIdx.x * 256 + threadIdx.x;
    int c = (i < n) ? counts[(long long)i * stride] : 0;
    for (int off = 32; off > 0; off >>= 1) c += __shfl_down(c, off, 64);
    __shared__ int sdata[4];
    int lane = threadIdx.x & 63, wave = threadIdx.x >> 6;
    if (lane == 0) sdata[wave] = c;
    __syncthreads();
    if (threadIdx.x == 0)
        blockSums[blockIdx.x] = sdata[0] + sdata[1] + sdata[2] + sdata[3];
}

// ---------------------------------------------------------------------------
// Kernel B: single-block exclusive scan of blockSums[nb] -> blockOffs[nb]
// ---------------------------------------------------------------------------
__global__ void k_scan_blocks(const int* __restrict__ blockSums, int nb,
                              int* __restrict__ blockOffs) {
    int t = threadIdx.x;
    int per = (nb + 255) / 256;
    int start = t * per;
    int end = min(start + per, nb);
    int sum = 0;
    for (int j = start; j < end; ++j) sum += blockSums[j];
    __shared__ int s[256];
    s[t] = sum;
    __syncthreads();
    for (int d = 1; d < 256; d <<= 1) {
        int v = (t >= d) ? s[t - d] : 0;
        __syncthreads();
        s[t] += v;
        __syncthreads();
    }
    int run = s[t] - sum;
    for (int j = start; j < end; ++j) {
        blockOffs[j] = run;
        run += blockSums[j];
    }
}

// ---------------------------------------------------------------------------
// Kernel C: one thread per prediction. Wave-shuffle scan (1 barrier), block's
// contiguous target window staged through LDS in CHUNK-row pieces with
// register-batched coalesced float2 loads + next-chunk prefetch overlapping
// the argmin compute.
// ---------------------------------------------------------------------------
__global__ __launch_bounds__(256) void k_loss(
    const float* __restrict__ pred, const float* __restrict__ tgt,
    const int* __restrict__ counts, int stride, int n,
    const int* __restrict__ blockOffs, float invN, float* __restrict__ out) {
    __shared__ float2 ch[CHUNK * 3];  // 24 KB
    __shared__ int wsum[4];
    __shared__ float fs[4];

    int t = threadIdx.x;
    int lane = t & 63, wave = t >> 6;
    int i = blockIdx.x * 256 + t;
    int c = (i < n) ? counts[(long long)i * stride] : 0;

    // wave-level inclusive scan of counts (no barriers)
    int incl = c;
#pragma unroll
    for (int d = 1; d < 64; d <<= 1) {
        int v = __shfl_up(incl, d, 64);
        if (lane >= d) incl += v;
    }
    if (lane == 63) wsum[wave] = incl;
    __syncthreads();
    int w0 = wsum[0], w1 = wsum[1], w2 = wsum[2], w3 = wsum[3];
    int waveOff = (wave > 0 ? w0 : 0) + (wave > 1 ? w1 : 0) + (wave > 2 ? w2 : 0);
    int off = waveOff + incl - c;       // exclusive prefix within block
    int total = w0 + w1 + w2 + w3;      // rows this block consumes
    int winStart = blockOffs[blockIdx.x];

    bool active = (i < n) && (c > 0);
    float p0 = 0, p1 = 0, p2 = 0, p3 = 0, p4 = 0;
    if (active) {
        const float2* p2p = (const float2*)(pred + (long long)i * 6);
        float2 a = p2p[0], b = p2p[1], w = p2p[2];
        p0 = a.x; p1 = a.y; p2 = b.x; p3 = b.y; p4 = w.x;
    }

    float best = INFINITY;
    float b0 = 0, b1 = 0, b2 = 0, b3 = 0, b4 = 0;

    const float2* win = (const float2*)tgt + (long long)winStart * 3;
    float2 r[F2PT];

    // prologue: prefetch chunk 0 into registers (batched independent loads)
    {
        int nF2 = min(CHUNK, total) * 3;
#pragma unroll
        for (int j = 0; j < F2PT; ++j) {
            int k = t + 256 * j;
            if (k < nF2) r[j] = win[k];
        }
    }

    for (int base = 0; base < total; base += CHUNK) {
        int rows = min(CHUNK, total - base);
        int nF2c = rows * 3;
        // registers -> LDS (one batch, one waitcnt)
#pragma unroll
        for (int j = 0; j < F2PT; ++j) {
            int k = t + 256 * j;
            if (k < nF2c) ch[k] = r[j];
        }
        __syncthreads();
        // prefetch next chunk while computing this one
        int nbase = base + CHUNK;
        if (nbase < total) {
            int nF2n = min(CHUNK, total - nbase) * 3;
            const float2* srcn = win + (long long)nbase * 3;
#pragma unroll
            for (int j = 0; j < F2PT; ++j) {
                int k = t + 256 * j;
                if (k < nF2n) r[j] = srcn[k];
            }
        }
        if (active) {
            int lo = max(off, base), hi = min(off + c, base + rows);
            for (int rr = lo; rr < hi; ++rr) {
                int l3 = (rr - base) * 3;
                float2 ga = ch[l3], gb = ch[l3 + 1], gw = ch[l3 + 2];
                float d0 = p0 - ga.x, d1 = p1 - ga.y;
                float d2 = p2 - gb.x, d3 = p3 - gb.y;
                float d4 = p4 - gw.x;
                float dist = POS_W * (d0 * d0 + d1 * d1) +
                             ANG_W * (d2 * d2 + d3 * d3) + WID_W * d4 * d4;
                if (dist < best) {  // strict <: first occurrence, matches ref
                    best = dist;
                    b0 = ga.x; b1 = ga.y; b2 = gb.x; b3 = gb.y; b4 = gw.x;
                }
            }
        }
        __syncthreads();
    }

    float loss = 0.0f;
    if (active) {
        loss = POS_W * (smooth_l1(p0 - b0) + smooth_l1(p1 - b1)) +
               ANG_W * (fabsf(p2 - b2) + fabsf(p3 - b3)) +
               WID_W * smooth_l1(p4 - b4);
    }

    for (int o = 32; o > 0; o >>= 1) loss += __shfl_down(loss, o, 64);
    if (lane == 0) fs[wave] = loss;
    __syncthreads();
    if (t == 0) {
        float tot = (fs[0] + fs[1] + fs[2] + fs[3]) * invN;
        atomicAdd(out, tot);
    }
}

// ---------------------------------------------------------------------------
extern "C" void kernel_launch(void* const* d_in, const int* in_sizes, int n_in,
                              void* d_out, int out_size, void* d_ws,
                              size_t ws_size, hipStream_t stream) {
    const float* pred = (const float*)d_in[0];
    const float* tgt = (const float*)d_in[1];
    const int* counts = (const int*)d_in[2];
    int n = in_sizes[0] / 6;
    int stride = (in_sizes[2] == n) ? 1 : 2;  // int64 counts -> read low words
    int nb = (n + 255) / 256;

    int* blockSums = (int*)d_ws;
    int* blockOffs = blockSums + nb;
    float* out = (float*)d_out;

    hipMemsetAsync(d_out, 0, sizeof(float), stream);
    k_block_sums<<<nb, 256, 0, stream>>>(counts, stride, n, blockSums);
    k_scan_blocks<<<1, 256, 0, stream>>>(blockSums, nb, blockOffs);
    k_loss<<<nb, 256, 0, stream>>>(pred, tgt, counts, stride, n, blockOffs,
                                   1.0f / n, out);
}